// Round 1
// baseline (3641.290 us; speedup 1.0000x reference)
//
#include <hip/hip_runtime.h>

#define NN 50000
#define EE 400000

// relation tables: src(r) = r/4
__constant__ int DSTT[20]     = {1,2,3,4, 2,0,3,4, 0,1,3,4, 0,1,2,4, 0,2,3,1};
__constant__ int KIDX[20]     = {0,0,0,0, 1,0,1,1, 1,1,2,2, 2,2,2,3, 3,3,3,3};
__constant__ int DSTREL[5][4] = {{5,8,12,16},{0,9,13,19},{1,4,14,17},{2,6,10,18},{3,7,11,15}};

// workspace element offsets (floats/ints, 4B each)
#define OFF_DEGO 0          // 20*50000 int
#define OFF_DEGI 1000000    // 20*50000 int
#define OFF_C    2000000    // 20*50000 f  (craw -> c in place)
#define OFF_S    3000000    // 20 f
#define OFF_MACC 3000064    // 128 f
#define OFF_DACC 3000192    // 80*50000 f
#define OFF_Y    7000192    // 80*768 f
#define OFF_V    7061632    // 20*128 f
#define OFF_PART 7064192    // 64*80*768 f
#define ZERO_ELEMS 10996352
#define OFF_NS   10996352   // 20*50000 f
#define OFF_ND   11996352   // 20*50000 f
#define OFF_CC   12996352   // 20*50000*4 f
#define TOTAL_ELEMS 16996352

static __device__ __forceinline__ void fma4(float4& a, const float4& x, float w) {
    a.x += w * x.x; a.y += w * x.y; a.z += w * x.z; a.w += w * x.w;
}

__global__ void k_deg(const int* __restrict__ edges, int* __restrict__ dego, int* __restrict__ degi) {
    int r = blockIdx.y;
    int e = blockIdx.x * 256 + threadIdx.x;
    if (e >= EE) return;
    int s = edges[(r*2+0)*EE + e];
    int d = edges[(r*2+1)*EE + e];
    atomicAdd(&dego[r*NN + s], 1);
    atomicAdd(&degi[r*NN + d], 1);
}

__global__ void k_norms(const int* __restrict__ dego, const int* __restrict__ degi,
                        float* __restrict__ ns, float* __restrict__ nd) {
    int r = blockIdx.y;
    int u = blockIdx.x * 256 + threadIdx.x;
    if (u >= NN) return;
    float dop = (float)dego[r*NN + u]; if (dop < 1.f) dop = 1.f;
    float dip = (float)degi[r*NN + u]; if (dip < 1.f) dip = 1.f;
    ns[r*NN + u] = 1.0f / sqrtf(dop);
    nd[r*NN + u] = 1.0f / sqrtf(dip);
}

__global__ void k_c(const int* __restrict__ edges, const float* __restrict__ nd, float* __restrict__ craw) {
    int r = blockIdx.y;
    int e = blockIdx.x * 256 + threadIdx.x;
    if (e >= EE) return;
    int s = edges[(r*2+0)*EE + e];
    int d = edges[(r*2+1)*EE + e];
    atomicAdd(&craw[r*NN + s], nd[r*NN + d]);
}

__global__ __launch_bounds__(256) void k_cS(const float* __restrict__ ns, float* __restrict__ c,
                                            float* __restrict__ S) {
    int r = blockIdx.y;
    int u = blockIdx.x * 256 + threadIdx.x;
    float val = 0.f;
    if (u < NN) {
        val = ns[r*NN + u] * c[r*NN + u];
        c[r*NN + u] = val;
    }
    for (int off = 32; off > 0; off >>= 1) val += __shfl_down(val, off, 64);
    __shared__ float red[4];
    if ((threadIdx.x & 63) == 0) red[threadIdx.x >> 6] = val;
    __syncthreads();
    if (threadIdx.x == 0) atomicAdd(&S[r], red[0] + red[1] + red[2] + red[3]);
}

// cc4[r1][u] = { c[4*dst(r1)+j][u] * nd[r1][u] : j=0..3 }  -> one float4 per (r1,dst-node)
__global__ void k_cc(const float* __restrict__ c, const float* __restrict__ nd, float* __restrict__ cc4) {
    int r1 = blockIdx.y;
    int u = blockIdx.x * 256 + threadIdx.x;
    if (u >= NN) return;
    float ndv = nd[r1*NN + u];
    int d1 = DSTT[r1];
    float4 w;
    w.x = c[(4*d1+0)*NN + u] * ndv;
    w.y = c[(4*d1+1)*NN + u] * ndv;
    w.z = c[(4*d1+2)*NN + u] * ndv;
    w.w = c[(4*d1+3)*NN + u] * ndv;
    *(float4*)(cc4 + (r1*NN + u) * 4) = w;
}

__global__ void k_d(const int* __restrict__ edges, const float* __restrict__ cc4, float* __restrict__ dacc) {
    int r1 = blockIdx.y;
    int e = blockIdx.x * 256 + threadIdx.x;
    if (e >= EE) return;
    int s = edges[(r1*2+0)*EE + e];
    int d = edges[(r1*2+1)*EE + e];
    float4 w = *(const float4*)(cc4 + (r1*NN + d) * 4);
    int d1 = DSTT[r1];
    int kk = KIDX[r1];
    atomicAdd(&dacc[(4*(4*d1+0)+kk)*NN + s], w.x);
    atomicAdd(&dacc[(4*(4*d1+1)+kk)*NN + s], w.y);
    atomicAdd(&dacc[(4*(4*d1+2)+kk)*NN + s], w.z);
    atomicAdd(&dacc[(4*(4*d1+3)+kk)*NN + s], w.w);
}

// y[p][0:768] += sum_u ns[r1][u]*dacc[p][u] * x[u][:]   for the 16 pairs of src ntype s1 (F=768)
__global__ __launch_bounds__(192) void k_y_big(const float* __restrict__ x,
        const float* __restrict__ ns, const float* __restrict__ dacc,
        float* __restrict__ partial, int s1) {
    __shared__ float wlds[64 * 20];
    const int tid = threadIdx.x;
    const int u0 = blockIdx.x * 64;
    for (int t = tid; t < 1024; t += 192) {
        int q = t >> 6, ri = t & 63;
        int i = q >> 2, j = q & 3;
        int r1 = 4*s1 + i;
        int d1 = DSTT[r1];
        int p = 4*(4*d1 + j) + KIDX[r1];
        int u = u0 + ri;
        float w = 0.f;
        if (u < NN) w = ns[r1*NN + u] * dacc[p*NN + u];
        wlds[ri*20 + q] = w;
    }
    __syncthreads();
    float4 acc[16];
#pragma unroll
    for (int q = 0; q < 16; ++q) acc[q] = make_float4(0.f, 0.f, 0.f, 0.f);
    const int c0 = tid * 4;
    const int rmax = (NN - u0 < 64) ? (NN - u0) : 64;
    for (int ri = 0; ri < rmax; ++ri) {
        const float4 xv = *(const float4*)(x + (u0 + ri) * 768 + c0);
        const float4* wp = (const float4*)(wlds + ri * 20);
#pragma unroll
        for (int g = 0; g < 4; ++g) {
            float4 w4 = wp[g];
            fma4(acc[4*g+0], xv, w4.x);
            fma4(acc[4*g+1], xv, w4.y);
            fma4(acc[4*g+2], xv, w4.z);
            fma4(acc[4*g+3], xv, w4.w);
        }
    }
    float* pslot = partial + (blockIdx.x & 63) * (80 * 768);
#pragma unroll
    for (int q = 0; q < 16; ++q) {
        int i = q >> 2, j = q & 3;
        int r1 = 4*s1 + i;
        int p = 4*(4*DSTT[r1] + j) + KIDX[r1];
        float* yp = pslot + p * 768 + c0;
        atomicAdd(yp + 0, acc[q].x);
        atomicAdd(yp + 1, acc[q].y);
        atomicAdd(yp + 2, acc[q].z);
        atomicAdd(yp + 3, acc[q].w);
    }
}

// small-F variant: one block per (f, q, chunk); dot of weight vector with x column f
__global__ __launch_bounds__(256) void k_y_small(const float* __restrict__ x,
        const float* __restrict__ ns, const float* __restrict__ dacc,
        float* __restrict__ partial, int s1, int F) {
    const int f = blockIdx.x;
    const int q = blockIdx.y;
    const int i = q >> 2, j = q & 3;
    const int r1 = 4*s1 + i;
    const int p = 4*(4*DSTT[r1] + j) + KIDX[r1];
    const float* nsp = ns + r1*NN;
    const float* dp = dacc + p*NN;
    const int uend = (blockIdx.z + 1) * 12500;
    float sum = 0.f;
    for (int u = blockIdx.z * 12500 + threadIdx.x; u < uend; u += 256)
        sum += nsp[u] * dp[u] * x[u*F + f];
    for (int off = 32; off > 0; off >>= 1) sum += __shfl_down(sum, off, 64);
    __shared__ float red[4];
    if ((threadIdx.x & 63) == 0) red[threadIdx.x >> 6] = sum;
    __syncthreads();
    if (threadIdx.x == 0)
        atomicAdd(&partial[p * 768 + f], red[0] + red[1] + red[2] + red[3]);
}

__global__ void k_red_y(const float* __restrict__ partial, float* __restrict__ y) {
    int idx = blockIdx.x * 256 + threadIdx.x;
    if (idx >= 80 * 768) return;
    float s = 0.f;
    for (int i = 0; i < 64; ++i) s += partial[i * 80 * 768 + idx];
    y[idx] = s;
}

__constant__ int FEATS[5] = {5, 16, 21, 768, 768};

// v[r2][c] += sum_f y[p][f] * W1[r1][f][c]
__global__ __launch_bounds__(128) void k_v(const float* __restrict__ y,
        const float* __restrict__ W1s, const float* __restrict__ W1f, const float* __restrict__ W1m,
        const float* __restrict__ W1n, const float* __restrict__ W1p, float* __restrict__ v) {
    int p = blockIdx.x;
    int c = threadIdx.x;
    int r2 = p >> 2, k = p & 3;
    int r1 = DSTREL[r2 >> 2][k];
    int s1 = r1 >> 2;
    int F = FEATS[s1];
    const float* W1 = (s1 == 0 ? W1s : s1 == 1 ? W1f : s1 == 2 ? W1m : s1 == 3 ? W1n : W1p)
                      + (r1 & 3) * F * 128;
    const float* yp = y + p * 768;
    float sum = 0.f;
    for (int f = 0; f < F; ++f) sum += yp[f] * W1[f * 128 + c];
    atomicAdd(&v[r2 * 128 + c], sum);
}

// macc[c] += sum_k (v[r2][k] + S[r2]*bsum1_{src(r2)}[k]) * W2[r2][k][c]
__global__ __launch_bounds__(128) void k_m(const float* __restrict__ v, const float* __restrict__ S,
        const float* __restrict__ b1, const float* __restrict__ W2, float* __restrict__ macc) {
    int r2 = blockIdx.x;
    int c = threadIdx.x;
    __shared__ float vp[128];
    int s2 = r2 >> 2;
    float b = b1[DSTREL[s2][0]*128 + c] + b1[DSTREL[s2][1]*128 + c]
            + b1[DSTREL[s2][2]*128 + c] + b1[DSTREL[s2][3]*128 + c];
    vp[c] = v[r2*128 + c] + S[r2] * b;
    __syncthreads();
    const float* W2r = W2 + r2 * 16384;
    float sum = 0.f;
    for (int k = 0; k < 128; ++k) sum += vp[k] * W2r[k * 128 + c];
    atomicAdd(&macc[c], sum);
}

__global__ __launch_bounds__(128) void k_out(const float* __restrict__ macc, const float* __restrict__ b2,
        const float* __restrict__ Wfc, const float* __restrict__ bfc, float* __restrict__ out) {
    int c = threadIdx.x;
    __shared__ float ml[128];
    float bs = 0.f;
    for (int r2 = 0; r2 < 20; ++r2) bs += b2[r2 * 128 + c];
    float m = (macc[c] + (float)NN * bs) * (1.0f / (5.0f * (float)NN));
    out[c] = m;
    ml[c] = m;
    __syncthreads();
    if (c < 10) {
        float o = bfc[c];
        for (int k = 0; k < 128; ++k) o += ml[k] * Wfc[k * 10 + c];
        out[128 + c] = o;
    }
}

extern "C" void kernel_launch(void* const* d_in, const int* in_sizes, int n_in,
                              void* d_out, int out_size, void* d_ws, size_t ws_size,
                              hipStream_t stream) {
    (void)in_sizes; (void)n_in; (void)out_size;
    const float* xs  = (const float*)d_in[0];
    const float* xf  = (const float*)d_in[1];
    const float* xm  = (const float*)d_in[2];
    const float* xn  = (const float*)d_in[3];
    const float* xp  = (const float*)d_in[4];
    const float* W1s = (const float*)d_in[5];
    const float* W1f = (const float*)d_in[6];
    const float* W1m = (const float*)d_in[7];
    const float* W1n = (const float*)d_in[8];
    const float* W1p = (const float*)d_in[9];
    const float* b1  = (const float*)d_in[10];
    const float* W2  = (const float*)d_in[11];
    const float* b2  = (const float*)d_in[12];
    const float* Wfc = (const float*)d_in[13];
    const float* bfc = (const float*)d_in[14];
    const int* edges = (const int*)d_in[15];
    float* ws = (float*)d_ws;
    int* wsi = (int*)d_ws;
    float* out = (float*)d_out;
    if (ws_size < (size_t)TOTAL_ELEMS * 4) return;

    hipMemsetAsync(d_ws, 0, (size_t)ZERO_ELEMS * 4, stream);

    dim3 eb(1563, 20), nb(196, 20), t256(256);
    k_deg<<<eb, t256, 0, stream>>>(edges, wsi + OFF_DEGO, wsi + OFF_DEGI);
    k_norms<<<nb, t256, 0, stream>>>(wsi + OFF_DEGO, wsi + OFF_DEGI, ws + OFF_NS, ws + OFF_ND);
    k_c<<<eb, t256, 0, stream>>>(edges, ws + OFF_ND, ws + OFF_C);
    k_cS<<<nb, t256, 0, stream>>>(ws + OFF_NS, ws + OFF_C, ws + OFF_S);
    k_cc<<<nb, t256, 0, stream>>>(ws + OFF_C, ws + OFF_ND, ws + OFF_CC);
    k_d<<<eb, t256, 0, stream>>>(edges, ws + OFF_CC, ws + OFF_DACC);
    k_y_big<<<dim3(782), dim3(192), 0, stream>>>(xn, ws + OFF_NS, ws + OFF_DACC, ws + OFF_PART, 3);
    k_y_big<<<dim3(782), dim3(192), 0, stream>>>(xp, ws + OFF_NS, ws + OFF_DACC, ws + OFF_PART, 4);
    k_y_small<<<dim3(5, 16, 4), t256, 0, stream>>>(xs, ws + OFF_NS, ws + OFF_DACC, ws + OFF_PART, 0, 5);
    k_y_small<<<dim3(16, 16, 4), t256, 0, stream>>>(xf, ws + OFF_NS, ws + OFF_DACC, ws + OFF_PART, 1, 16);
    k_y_small<<<dim3(21, 16, 4), t256, 0, stream>>>(xm, ws + OFF_NS, ws + OFF_DACC, ws + OFF_PART, 2, 21);
    k_red_y<<<dim3(240), t256, 0, stream>>>(ws + OFF_PART, ws + OFF_Y);
    k_v<<<dim3(80), dim3(128), 0, stream>>>(ws + OFF_Y, W1s, W1f, W1m, W1n, W1p, ws + OFF_V);
    k_m<<<dim3(20), dim3(128), 0, stream>>>(ws + OFF_V, ws + OFF_S, b1, W2, ws + OFF_MACC);
    k_out<<<dim3(1), dim3(128), 0, stream>>>(ws + OFF_MACC, b2, Wfc, bfc, out);
}

// Round 2
// 3077.028 us; speedup vs baseline: 1.1834x; 1.1834x over previous
//
#include <hip/hip_runtime.h>

#define NN 50000
#define EE 400000

#define CHUNK_H 16384     // hist/craw chunk (64KB LDS: int/float)
#define NCH_H 4           // 4*16384 = 65536 >= 50000
#define CHUNK_D 4096      // dacc chunk (float4 -> 64KB LDS)
#define NCH_D 13          // 13*4096 = 53248 >= 50000
#define ESL 2             // edge slices per chunk-job
#define EPS (EE/ESL)      // 200000
#define NZ 112            // k_y_big row-chunks (PART slots)
#define ZROWS 448         // 112*448 = 50176 >= 50000 (7 tiles of 64)

// relation tables: src(r) = r/4
__constant__ int DSTT[20]     = {1,2,3,4, 2,0,3,4, 0,1,3,4, 0,1,2,4, 0,2,3,1};
__constant__ int KIDX[20]     = {0,0,0,0, 1,0,1,1, 1,1,2,2, 2,2,2,3, 3,3,3,3};
__constant__ int DSTREL[5][4] = {{5,8,12,16},{0,9,13,19},{1,4,14,17},{2,6,10,18},{3,7,11,15}};
__constant__ int FEATS[5]     = {5, 16, 21, 768, 768};

// ---- workspace arena (float element offsets) ----
// Region A [0 : 8,000,000):
//   OFF_HIST = 0        ints  [4 x 1,000,000]   (steps hist->norms)
//   OFF_CRAW = 0        float [2 x 1,000,000]   (steps craw->cS)
//   OFF_CC4  = 2,000,000 float [4,000,000]      (steps cc->dacc)
//   OFF_S    = 6,950,000 float [64]             (step cS -> k_m; outside PART)
//   OFF_NS   = 7,000,000 float [1,000,000]      (norms -> k_y)
//   OFF_PART = 0        float [112*61440=6,881,280] (memset after dacc; y phase)
// Region B [8,000,000 : 16,000,000):
//   OFF_C    = 8,000,000 float [1,000,000]      (cS -> cc)
//   OFF_ND   = 9,000,000 float [1,000,000]      (norms -> cc)
//   OFF_DACC = 8,000,000 float [2 x 4,000,000]  (dacc -> k_y)
//   OFF_Y    = 8,000,000 float [61,440]         (red_y -> k_v; dacc dead)
//   OFF_V    = 8,061,504 float [2,560]
//   OFF_MACC = 8,064,064 float [128]
#define OFF_HIST 0
#define OFF_CRAW 0
#define OFF_CC4  2000000
#define OFF_S    6950000
#define OFF_NS   7000000
#define OFF_PART 0
#define OFF_C    8000000
#define OFF_ND   9000000
#define OFF_DACC 8000000
#define DSLICE   4000000
#define OFF_Y    8000000
#define OFF_V    8061504
#define OFF_MACC 8064064
#define TOTAL_ELEMS 16000000

static __device__ __forceinline__ void fma4(float4& a, const float4& x, float w) {
    a.x += w * x.x; a.y += w * x.y; a.z += w * x.z; a.w += w * x.w;
}

// LDS-chunked histogram: z = arr*20 + r; arr 0: src (dego), 1: dst (degi)
__global__ __launch_bounds__(256) void k_hist(const int* __restrict__ edges, int* __restrict__ hist_part) {
    __shared__ int h[CHUNK_H];
    const int slice = blockIdx.x, chunk = blockIdx.y;
    const int r = blockIdx.z % 20, arr = blockIdx.z / 20;
    for (int i = threadIdx.x; i < CHUNK_H; i += 256) h[i] = 0;
    __syncthreads();
    const int* key = edges + (size_t)(r*2 + arr)*EE + slice*EPS;
    const int base = chunk * CHUNK_H;
#pragma unroll 4
    for (int e = threadIdx.x; e < EPS; e += 256) {
        unsigned k = (unsigned)(key[e] - base);
        if (k < CHUNK_H) atomicAdd(&h[k], 1);
    }
    __syncthreads();
    int* outp = hist_part + (arr*ESL + slice)*1000000 + r*NN;
    for (int i = threadIdx.x; i < CHUNK_H; i += 256) {
        int u = base + i;
        if (u < NN) outp[u] = h[i];
    }
}

__global__ __launch_bounds__(256) void k_norms(const int* __restrict__ hist_part,
                                               float* __restrict__ ns, float* __restrict__ nd) {
    int r = blockIdx.y;
    int u = blockIdx.x * 256 + threadIdx.x;
    if (u >= NN) return;
    int idx = r*NN + u;
    float dop = (float)(hist_part[idx] + hist_part[1000000 + idx]);
    float dip = (float)(hist_part[2000000 + idx] + hist_part[3000000 + idx]);
    if (dop < 1.f) dop = 1.f;
    if (dip < 1.f) dip = 1.f;
    ns[idx] = 1.0f / sqrtf(dop);
    nd[idx] = 1.0f / sqrtf(dip);
}

// craw[s] = sum_{e:src=s} nd[dst]; LDS-chunked, per-slice copies
__global__ __launch_bounds__(256) void k_craw(const int* __restrict__ edges,
                                              const float* __restrict__ nd, float* __restrict__ craw_part) {
    __shared__ float h[CHUNK_H];
    const int slice = blockIdx.x, chunk = blockIdx.y, r = blockIdx.z;
    for (int i = threadIdx.x; i < CHUNK_H; i += 256) h[i] = 0.f;
    __syncthreads();
    const int* srcp = edges + (size_t)(r*2)*EE + slice*EPS;
    const int* dstp = srcp + EE;
    const float* ndr = nd + r*NN;
    const int base = chunk * CHUNK_H;
#pragma unroll 4
    for (int e = threadIdx.x; e < EPS; e += 256) {
        unsigned k = (unsigned)(srcp[e] - base);
        if (k < CHUNK_H) {
            int d = dstp[e];
            atomicAdd(&h[k], ndr[d]);
        }
    }
    __syncthreads();
    float* outp = craw_part + slice*1000000 + r*NN;
    for (int i = threadIdx.x; i < CHUNK_H; i += 256) {
        int u = base + i;
        if (u < NN) outp[u] = h[i];
    }
}

__global__ __launch_bounds__(256) void k_cS(const float* __restrict__ craw_part, const float* __restrict__ ns,
                                            float* __restrict__ c, float* __restrict__ S) {
    int r = blockIdx.y;
    int u = blockIdx.x * 256 + threadIdx.x;
    float val = 0.f;
    if (u < NN) {
        int idx = r*NN + u;
        val = ns[idx] * (craw_part[idx] + craw_part[1000000 + idx]);
        c[idx] = val;
    }
    for (int off = 32; off > 0; off >>= 1) val += __shfl_down(val, off, 64);
    __shared__ float red[4];
    if ((threadIdx.x & 63) == 0) red[threadIdx.x >> 6] = val;
    __syncthreads();
    if (threadIdx.x == 0) atomicAdd(&S[r], red[0] + red[1] + red[2] + red[3]);
}

// cc4[r1][u] = { c[4*dst(r1)+j][u] * nd[r1][u] : j=0..3 }
__global__ __launch_bounds__(256) void k_cc(const float* __restrict__ c, const float* __restrict__ nd,
                                            float* __restrict__ cc4) {
    int r1 = blockIdx.y;
    int u = blockIdx.x * 256 + threadIdx.x;
    if (u >= NN) return;
    float ndv = nd[r1*NN + u];
    int d1 = DSTT[r1];
    float4 w;
    w.x = c[(4*d1+0)*NN + u] * ndv;
    w.y = c[(4*d1+1)*NN + u] * ndv;
    w.z = c[(4*d1+2)*NN + u] * ndv;
    w.w = c[(4*d1+3)*NN + u] * ndv;
    *(float4*)(cc4 + (size_t)(r1*NN + u) * 4) = w;
}

// dacc[p][s] = sum_{e in r1, src=s} cc_j[dst]; LDS-chunked float4, per-slice copies
__global__ __launch_bounds__(256) void k_dacc(const int* __restrict__ edges,
                                              const float* __restrict__ cc4, float* __restrict__ dacc_part) {
    __shared__ float h4[CHUNK_D * 4];
    const int slice = blockIdx.x, chunk = blockIdx.y, r = blockIdx.z;
    for (int i = threadIdx.x; i < CHUNK_D * 4; i += 256) h4[i] = 0.f;
    __syncthreads();
    const int* srcp = edges + (size_t)(r*2)*EE + slice*EPS;
    const int* dstp = srcp + EE;
    const float* ccr = cc4 + (size_t)r*NN*4;
    const int base = chunk * CHUNK_D;
#pragma unroll 4
    for (int e = threadIdx.x; e < EPS; e += 256) {
        unsigned k = (unsigned)(srcp[e] - base);
        if (k < CHUNK_D) {
            int d = dstp[e];
            const float4 w = *(const float4*)(ccr + (size_t)d * 4);
            atomicAdd(&h4[k*4+0], w.x);
            atomicAdd(&h4[k*4+1], w.y);
            atomicAdd(&h4[k*4+2], w.z);
            atomicAdd(&h4[k*4+3], w.w);
        }
    }
    __syncthreads();
    const int d1 = DSTT[r], kk = KIDX[r];
    float* op = dacc_part + slice * DSLICE;
#pragma unroll
    for (int j = 0; j < 4; ++j) {
        int p = 4*(4*d1 + j) + kk;
        float* pj = op + (size_t)p*NN;
        for (int i = threadIdx.x; i < CHUNK_D; i += 256) {
            int u = base + i;
            if (u < NN) pj[u] = h4[i*4 + j];
        }
    }
}

// y partials for the two 768-wide src ntypes; each block owns row-range z -> own PART slot (no atomics)
__global__ __launch_bounds__(192) void k_y_big(const float* __restrict__ xn, const float* __restrict__ xp,
        const float* __restrict__ ns, const float* __restrict__ dacc, float* __restrict__ partial) {
    __shared__ float wlds[64 * 20];
    const int tid = threadIdx.x;
    const int s1 = 3 + blockIdx.y;
    const float* x = (blockIdx.y == 0) ? xn : xp;
    const int z = blockIdx.x;
    const int c0 = tid * 4;
    float4 acc[16];
#pragma unroll
    for (int q = 0; q < 16; ++q) acc[q] = make_float4(0.f, 0.f, 0.f, 0.f);

    for (int t = 0; t < 7; ++t) {
        const int u0 = z * ZROWS + t * 64;
        __syncthreads();
        for (int tt = tid; tt < 1024; tt += 192) {
            int q = tt >> 6, ri = tt & 63;
            int i = q >> 2, j = q & 3;
            int r1 = 4*s1 + i;
            int p = 4*(4*DSTT[r1] + j) + KIDX[r1];
            int u = u0 + ri;
            float w = 0.f;
            if (u < NN) {
                int idx = p*NN + u;
                w = ns[r1*NN + u] * (dacc[idx] + dacc[DSLICE + idx]);
            }
            wlds[ri*20 + q] = w;
        }
        __syncthreads();
        const int rmax = (NN - u0 < 64) ? (NN - u0) : 64;
        for (int ri = 0; ri < rmax; ++ri) {
            const float4 xv = *(const float4*)(x + (size_t)(u0 + ri) * 768 + c0);
            const float4* wp = (const float4*)(wlds + ri * 20);
#pragma unroll
            for (int g = 0; g < 4; ++g) {
                float4 w4 = wp[g];
                fma4(acc[4*g+0], xv, w4.x);
                fma4(acc[4*g+1], xv, w4.y);
                fma4(acc[4*g+2], xv, w4.z);
                fma4(acc[4*g+3], xv, w4.w);
            }
        }
    }
    float* pslot = partial + (size_t)z * (80 * 768);
#pragma unroll
    for (int q = 0; q < 16; ++q) {
        int i = q >> 2, j = q & 3;
        int r1 = 4*s1 + i;
        int p = 4*(4*DSTT[r1] + j) + KIDX[r1];
        *(float4*)(pslot + p * 768 + c0) = acc[q];
    }
}

// small-F: dot of weight vector with x column f; few atomics (1 per block) into PART slot 0
__global__ __launch_bounds__(256) void k_y_small(const float* __restrict__ x,
        const float* __restrict__ ns, const float* __restrict__ dacc,
        float* __restrict__ partial, int s1, int F) {
    const int f = blockIdx.x;
    const int q = blockIdx.y;
    const int i = q >> 2, j = q & 3;
    const int r1 = 4*s1 + i;
    const int p = 4*(4*DSTT[r1] + j) + KIDX[r1];
    const float* nsp = ns + r1*NN;
    const float* dp0 = dacc + (size_t)p*NN;
    const float* dp1 = dp0 + DSLICE;
    const int uend = (blockIdx.z + 1) * 12500;
    float sum = 0.f;
    for (int u = blockIdx.z * 12500 + threadIdx.x; u < uend; u += 256)
        sum += nsp[u] * (dp0[u] + dp1[u]) * x[(size_t)u*F + f];
    for (int off = 32; off > 0; off >>= 1) sum += __shfl_down(sum, off, 64);
    __shared__ float red[4];
    if ((threadIdx.x & 63) == 0) red[threadIdx.x >> 6] = sum;
    __syncthreads();
    if (threadIdx.x == 0)
        atomicAdd(&partial[p * 768 + f], red[0] + red[1] + red[2] + red[3]);
}

__global__ void k_red_y(const float* __restrict__ partial, float* __restrict__ y) {
    int idx = blockIdx.x * 256 + threadIdx.x;
    if (idx >= 80 * 768) return;
    float s = 0.f;
    for (int i = 0; i < NZ; ++i) s += partial[(size_t)i * 80 * 768 + idx];
    y[idx] = s;
}

// v[r2][c] += sum_f y[p][f] * W1[r1][f][c]
__global__ __launch_bounds__(128) void k_v(const float* __restrict__ y,
        const float* __restrict__ W1s, const float* __restrict__ W1f, const float* __restrict__ W1m,
        const float* __restrict__ W1n, const float* __restrict__ W1p, float* __restrict__ v) {
    int p = blockIdx.x;
    int c = threadIdx.x;
    int r2 = p >> 2, k = p & 3;
    int r1 = DSTREL[r2 >> 2][k];
    int s1 = r1 >> 2;
    int F = FEATS[s1];
    const float* W1 = (s1 == 0 ? W1s : s1 == 1 ? W1f : s1 == 2 ? W1m : s1 == 3 ? W1n : W1p)
                      + (r1 & 3) * F * 128;
    const float* yp = y + p * 768;
    float sum = 0.f;
    for (int f = 0; f < F; ++f) sum += yp[f] * W1[f * 128 + c];
    atomicAdd(&v[r2 * 128 + c], sum);
}

// macc[c] += sum_k (v[r2][k] + S[r2]*bsum1_{src(r2)}[k]) * W2[r2][k][c]
__global__ __launch_bounds__(128) void k_m(const float* __restrict__ v, const float* __restrict__ S,
        const float* __restrict__ b1, const float* __restrict__ W2, float* __restrict__ macc) {
    int r2 = blockIdx.x;
    int c = threadIdx.x;
    __shared__ float vp[128];
    int s2 = r2 >> 2;
    float b = b1[DSTREL[s2][0]*128 + c] + b1[DSTREL[s2][1]*128 + c]
            + b1[DSTREL[s2][2]*128 + c] + b1[DSTREL[s2][3]*128 + c];
    vp[c] = v[r2*128 + c] + S[r2] * b;
    __syncthreads();
    const float* W2r = W2 + r2 * 16384;
    float sum = 0.f;
    for (int k = 0; k < 128; ++k) sum += vp[k] * W2r[k * 128 + c];
    atomicAdd(&macc[c], sum);
}

__global__ __launch_bounds__(128) void k_out(const float* __restrict__ macc, const float* __restrict__ b2,
        const float* __restrict__ Wfc, const float* __restrict__ bfc, float* __restrict__ out) {
    int c = threadIdx.x;
    __shared__ float ml[128];
    float bs = 0.f;
    for (int r2 = 0; r2 < 20; ++r2) bs += b2[r2 * 128 + c];
    float m = (macc[c] + (float)NN * bs) * (1.0f / (5.0f * (float)NN));
    out[c] = m;
    ml[c] = m;
    __syncthreads();
    if (c < 10) {
        float o = bfc[c];
        for (int k = 0; k < 128; ++k) o += ml[k] * Wfc[k * 10 + c];
        out[128 + c] = o;
    }
}

extern "C" void kernel_launch(void* const* d_in, const int* in_sizes, int n_in,
                              void* d_out, int out_size, void* d_ws, size_t ws_size,
                              hipStream_t stream) {
    (void)in_sizes; (void)n_in; (void)out_size;
    const float* xs  = (const float*)d_in[0];
    const float* xf  = (const float*)d_in[1];
    const float* xm  = (const float*)d_in[2];
    const float* xn  = (const float*)d_in[3];
    const float* xp  = (const float*)d_in[4];
    const float* W1s = (const float*)d_in[5];
    const float* W1f = (const float*)d_in[6];
    const float* W1m = (const float*)d_in[7];
    const float* W1n = (const float*)d_in[8];
    const float* W1p = (const float*)d_in[9];
    const float* b1  = (const float*)d_in[10];
    const float* W2  = (const float*)d_in[11];
    const float* b2  = (const float*)d_in[12];
    const float* Wfc = (const float*)d_in[13];
    const float* bfc = (const float*)d_in[14];
    const int* edges = (const int*)d_in[15];
    float* ws = (float*)d_ws;
    int* wsi = (int*)d_ws;
    float* out = (float*)d_out;
    if (ws_size < (size_t)TOTAL_ELEMS * 4) return;

    dim3 t256(256), nb(196, 20);

    hipMemsetAsync(ws + OFF_S, 0, 64 * 4, stream);
    k_hist<<<dim3(ESL, NCH_H, 40), t256, 0, stream>>>(edges, wsi + OFF_HIST);
    k_norms<<<nb, t256, 0, stream>>>(wsi + OFF_HIST, ws + OFF_NS, ws + OFF_ND);
    k_craw<<<dim3(ESL, NCH_H, 20), t256, 0, stream>>>(edges, ws + OFF_ND, ws + OFF_CRAW);
    k_cS<<<nb, t256, 0, stream>>>(ws + OFF_CRAW, ws + OFF_NS, ws + OFF_C, ws + OFF_S);
    k_cc<<<nb, t256, 0, stream>>>(ws + OFF_C, ws + OFF_ND, ws + OFF_CC4);
    k_dacc<<<dim3(ESL, NCH_D, 20), t256, 0, stream>>>(edges, ws + OFF_CC4, ws + OFF_DACC);
    hipMemsetAsync(ws + OFF_PART, 0, (size_t)NZ * 80 * 768 * 4, stream);
    k_y_big<<<dim3(NZ, 2), dim3(192), 0, stream>>>(xn, xp, ws + OFF_NS, ws + OFF_DACC, ws + OFF_PART);
    k_y_small<<<dim3(5, 16, 4), t256, 0, stream>>>(xs, ws + OFF_NS, ws + OFF_DACC, ws + OFF_PART, 0, 5);
    k_y_small<<<dim3(16, 16, 4), t256, 0, stream>>>(xf, ws + OFF_NS, ws + OFF_DACC, ws + OFF_PART, 1, 16);
    k_y_small<<<dim3(21, 16, 4), t256, 0, stream>>>(xm, ws + OFF_NS, ws + OFF_DACC, ws + OFF_PART, 2, 21);
    hipMemsetAsync(ws + OFF_V, 0, (2560 + 128) * 4, stream);
    k_red_y<<<dim3(240), t256, 0, stream>>>(ws + OFF_PART, ws + OFF_Y);
    k_v<<<dim3(80), dim3(128), 0, stream>>>(ws + OFF_Y, W1s, W1f, W1m, W1n, W1p, ws + OFF_V);
    k_m<<<dim3(20), dim3(128), 0, stream>>>(ws + OFF_V, ws + OFF_S, b1, W2, ws + OFF_MACC);
    k_out<<<dim3(1), dim3(128), 0, stream>>>(ws + OFF_MACC, b2, Wfc, bfc, out);
}

// Round 3
// 1506.604 us; speedup vs baseline: 2.4169x; 2.0424x over previous
//
#include <hip/hip_runtime.h>

#define NN 50000
#define EE 400000

// chunked-scan params
#define CH_H 16384            // 64 KB LDS (int/float)
#define NCH_H 4               // 4*16384 >= 50000
#define ESL_H 2
#define EPS_H (EE/ESL_H)      // 200000
#define I4_H (EPS_H/4)        // 50000 int4

#define ESL_C 4
#define EPS_C (EE/ESL_C)      // 100000
#define I4_C (EPS_C/4)        // 25000 int4

#define CH_D 4096             // float4 chunk -> 64 KB LDS
#define NCH_D 13              // 13*4096 >= 50000
#define ESL_D 2
#define EPS_D (EE/ESL_D)      // 200000
#define I4_D (EPS_D/4)        // 50000 int4

#define NZ 261                // k_y_big row-chunks (261*192 = 50112 >= 50000)
#define ZROWS 192             // 3 tiles of 64

// relation tables: src(r) = r/4
__constant__ int DSTT[20]     = {1,2,3,4, 2,0,3,4, 0,1,3,4, 0,1,2,4, 0,2,3,1};
__constant__ int KIDX[20]     = {0,0,0,0, 1,0,1,1, 1,1,2,2, 2,2,2,3, 3,3,3,3};
__constant__ int DSTREL[5][4] = {{5,8,12,16},{0,9,13,19},{1,4,14,17},{2,6,10,18},{3,7,11,15}};
__constant__ int FEATS[5]     = {5, 16, 21, 768, 768};

// ---- workspace arena (4B element offsets), phase-aliased ----
#define OFF_HIST 0           // 4 x 1M int   (hist -> norms)
#define OFF_CRAW 0           // 4 x 1M float (craw -> cS)
#define OFF_CC4  0           // 4M float     (cc -> dacc)
#define OFF_C    4000000     // 1M (cS -> cc)
#define OFF_ND   5000000     // 1M (norms -> cc/craw)
#define OFF_PART 0           // 1044 slots * 6144 = 6,414,336 (y_big -> red_y)
#define OFF_YS   6500000     // 61440 (y_small -> red_y)
#define OFF_S    6600000     // 64    (cS -> k_m)
#define OFF_NS   7000000     // 1M    (norms -> y)
#define OFF_DACC 8000000     // 2 x 4M (dacc -> y)
#define DSLICE   4000000
#define OFF_Y    8000000     // 61440 (red_y -> v; dacc dead)
#define OFF_V    8100000     // 2560
#define OFF_MP   8110000     // 2560
#define TOTAL_ELEMS 16000000

static __device__ __forceinline__ void fma4(float4& a, const float4& x, float w) {
    a.x += w * x.x; a.y += w * x.y; a.z += w * x.z; a.w += w * x.w;
}

// z = arr*20 + r; arr 0: src keys (dego), 1: dst keys (degi)
__global__ __launch_bounds__(1024) void k_hist(const int* __restrict__ edges, int* __restrict__ hist_part) {
    __shared__ int h[CH_H];
    const int slice = blockIdx.x, chunk = blockIdx.y;
    const int r = blockIdx.z % 20, arr = blockIdx.z / 20;
    for (int i = threadIdx.x; i < CH_H; i += 1024) h[i] = 0;
    __syncthreads();
    const int4* key = (const int4*)(edges + (size_t)(r*2 + arr)*EE + slice*EPS_H);
    const int base = chunk * CH_H;
    for (int i = threadIdx.x; i < I4_H; i += 1024) {
        int4 k4 = key[i];
        unsigned a = (unsigned)(k4.x - base), b = (unsigned)(k4.y - base);
        unsigned c = (unsigned)(k4.z - base), d = (unsigned)(k4.w - base);
        if (a < CH_H) atomicAdd(&h[a], 1);
        if (b < CH_H) atomicAdd(&h[b], 1);
        if (c < CH_H) atomicAdd(&h[c], 1);
        if (d < CH_H) atomicAdd(&h[d], 1);
    }
    __syncthreads();
    int* outp = hist_part + (arr*ESL_H + slice)*1000000 + r*NN;
    for (int i = threadIdx.x; i < CH_H; i += 1024) {
        int u = base + i;
        if (u < NN) outp[u] = h[i];
    }
}

__global__ __launch_bounds__(256) void k_norms(const int* __restrict__ hist_part,
                                               float* __restrict__ ns, float* __restrict__ nd) {
    int r = blockIdx.y;
    int u = blockIdx.x * 256 + threadIdx.x;
    if (u >= NN) return;
    int idx = r*NN + u;
    float dop = (float)(hist_part[idx] + hist_part[1000000 + idx]);
    float dip = (float)(hist_part[2000000 + idx] + hist_part[3000000 + idx]);
    if (dop < 1.f) dop = 1.f;
    if (dip < 1.f) dip = 1.f;
    ns[idx] = 1.0f / sqrtf(dop);
    nd[idx] = 1.0f / sqrtf(dip);
}

// craw[s] = sum_{e:src=s} nd[dst]
__global__ __launch_bounds__(1024) void k_craw(const int* __restrict__ edges,
                                               const float* __restrict__ nd, float* __restrict__ craw_part) {
    __shared__ float h[CH_H];
    const int slice = blockIdx.x, chunk = blockIdx.y, r = blockIdx.z;
    for (int i = threadIdx.x; i < CH_H; i += 1024) h[i] = 0.f;
    __syncthreads();
    const int4* s4 = (const int4*)(edges + (size_t)(r*2)*EE + slice*EPS_C);
    const int4* d4 = (const int4*)(edges + (size_t)(r*2+1)*EE + slice*EPS_C);
    const float* ndr = nd + r*NN;
    const int base = chunk * CH_H;
    for (int i = threadIdx.x; i < I4_C; i += 1024) {
        int4 s = s4[i];
        int4 d = d4[i];
        unsigned a = (unsigned)(s.x - base), b = (unsigned)(s.y - base);
        unsigned c = (unsigned)(s.z - base), e = (unsigned)(s.w - base);
        if (a < CH_H) atomicAdd(&h[a], ndr[d.x]);
        if (b < CH_H) atomicAdd(&h[b], ndr[d.y]);
        if (c < CH_H) atomicAdd(&h[c], ndr[d.z]);
        if (e < CH_H) atomicAdd(&h[e], ndr[d.w]);
    }
    __syncthreads();
    float* outp = craw_part + slice*1000000 + r*NN;
    for (int i = threadIdx.x; i < CH_H; i += 1024) {
        int u = base + i;
        if (u < NN) outp[u] = h[i];
    }
}

__global__ __launch_bounds__(256) void k_cS(const float* __restrict__ craw_part, const float* __restrict__ ns,
                                            float* __restrict__ c, float* __restrict__ S) {
    int r = blockIdx.y;
    int u = blockIdx.x * 256 + threadIdx.x;
    float val = 0.f;
    if (u < NN) {
        int idx = r*NN + u;
        val = ns[idx] * (craw_part[idx] + craw_part[1000000 + idx]
                       + craw_part[2000000 + idx] + craw_part[3000000 + idx]);
        c[idx] = val;
    }
    for (int off = 32; off > 0; off >>= 1) val += __shfl_down(val, off, 64);
    __shared__ float red[4];
    if ((threadIdx.x & 63) == 0) red[threadIdx.x >> 6] = val;
    __syncthreads();
    if (threadIdx.x == 0) atomicAdd(&S[r], red[0] + red[1] + red[2] + red[3]);
}

// cc4[r1][u] = { c[4*dst(r1)+j][u] * nd[r1][u] : j=0..3 }
__global__ __launch_bounds__(256) void k_cc(const float* __restrict__ c, const float* __restrict__ nd,
                                            float* __restrict__ cc4) {
    int r1 = blockIdx.y;
    int u = blockIdx.x * 256 + threadIdx.x;
    if (u >= NN) return;
    float ndv = nd[r1*NN + u];
    int d1 = DSTT[r1];
    float4 w;
    w.x = c[(4*d1+0)*NN + u] * ndv;
    w.y = c[(4*d1+1)*NN + u] * ndv;
    w.z = c[(4*d1+2)*NN + u] * ndv;
    w.w = c[(4*d1+3)*NN + u] * ndv;
    *(float4*)(cc4 + (size_t)(r1*NN + u) * 4) = w;
}

// dacc[p][s] = sum_{e in r1, src=s} cc_j[dst]
__global__ __launch_bounds__(1024) void k_dacc(const int* __restrict__ edges,
                                               const float* __restrict__ cc4, float* __restrict__ dacc_part) {
    __shared__ float h4[CH_D * 4];
    const int slice = blockIdx.x, chunk = blockIdx.y, r = blockIdx.z;
    for (int i = threadIdx.x; i < CH_D * 4; i += 1024) h4[i] = 0.f;
    __syncthreads();
    const int4* s4 = (const int4*)(edges + (size_t)(r*2)*EE + slice*EPS_D);
    const int4* d4 = (const int4*)(edges + (size_t)(r*2+1)*EE + slice*EPS_D);
    const float* ccr = cc4 + (size_t)r*NN*4;
    const int base = chunk * CH_D;
    for (int i = threadIdx.x; i < I4_D; i += 1024) {
        int4 s = s4[i];
        int4 d = d4[i];
        unsigned a = (unsigned)(s.x - base), b = (unsigned)(s.y - base);
        unsigned c = (unsigned)(s.z - base), e = (unsigned)(s.w - base);
        if (a < CH_D) {
            const float4 w = *(const float4*)(ccr + (size_t)d.x * 4);
            atomicAdd(&h4[a*4+0], w.x); atomicAdd(&h4[a*4+1], w.y);
            atomicAdd(&h4[a*4+2], w.z); atomicAdd(&h4[a*4+3], w.w);
        }
        if (b < CH_D) {
            const float4 w = *(const float4*)(ccr + (size_t)d.y * 4);
            atomicAdd(&h4[b*4+0], w.x); atomicAdd(&h4[b*4+1], w.y);
            atomicAdd(&h4[b*4+2], w.z); atomicAdd(&h4[b*4+3], w.w);
        }
        if (c < CH_D) {
            const float4 w = *(const float4*)(ccr + (size_t)d.z * 4);
            atomicAdd(&h4[c*4+0], w.x); atomicAdd(&h4[c*4+1], w.y);
            atomicAdd(&h4[c*4+2], w.z); atomicAdd(&h4[c*4+3], w.w);
        }
        if (e < CH_D) {
            const float4 w = *(const float4*)(ccr + (size_t)d.w * 4);
            atomicAdd(&h4[e*4+0], w.x); atomicAdd(&h4[e*4+1], w.y);
            atomicAdd(&h4[e*4+2], w.z); atomicAdd(&h4[e*4+3], w.w);
        }
    }
    __syncthreads();
    const int d1 = DSTT[r], kk = KIDX[r];
    float* op = dacc_part + slice * DSLICE;
#pragma unroll
    for (int j = 0; j < 4; ++j) {
        int p = 4*(4*d1 + j) + kk;
        float* pj = op + (size_t)p*NN;
        for (int i = threadIdx.x; i < CH_D; i += 1024) {
            int u = base + i;
            if (u < NN) pj[u] = h4[i*4 + j];
        }
    }
}

// y partials, 768-wide src ntypes. Block = (row-chunk z, half, group); 8 q's; own slot, no atomics.
__global__ __launch_bounds__(192) void k_y_big(const float* __restrict__ xn, const float* __restrict__ xp,
        const float* __restrict__ ns, const float* __restrict__ dacc, float* __restrict__ partial) {
    __shared__ float wlds[64 * 8];
    const int tid = threadIdx.x;
    const int z = blockIdx.x, half = blockIdx.y, group = blockIdx.z;
    const int s1 = 3 + group;
    const float* x = (group == 0) ? xn : xp;
    const int c0 = tid * 4;
    float4 acc[8];
#pragma unroll
    for (int q = 0; q < 8; ++q) acc[q] = make_float4(0.f, 0.f, 0.f, 0.f);

    for (int t = 0; t < 3; ++t) {
        const int u0 = z * ZROWS + t * 64;
        __syncthreads();
        for (int tt = tid; tt < 512; tt += 192) {
            int ql = tt >> 6, ri = tt & 63;
            int i = half*2 + (ql >> 2), j = ql & 3;
            int r1 = 4*s1 + i;
            int p = 4*(4*DSTT[r1] + j) + KIDX[r1];
            int u = u0 + ri;
            float w = 0.f;
            if (u < NN) {
                int idx = p*NN + u;
                w = ns[r1*NN + u] * (dacc[idx] + dacc[DSLICE + idx]);
            }
            wlds[ri*8 + ql] = w;
        }
        __syncthreads();
        const int rmax = (NN - u0 < 64) ? (NN - u0) : 64;
#pragma unroll 4
        for (int ri = 0; ri < rmax; ++ri) {
            const float4 xv = *(const float4*)(x + (size_t)(u0 + ri) * 768 + c0);
            const float4 wa = *(const float4*)(wlds + ri * 8);
            const float4 wb = *(const float4*)(wlds + ri * 8 + 4);
            fma4(acc[0], xv, wa.x); fma4(acc[1], xv, wa.y);
            fma4(acc[2], xv, wa.z); fma4(acc[3], xv, wa.w);
            fma4(acc[4], xv, wb.x); fma4(acc[5], xv, wb.y);
            fma4(acc[6], xv, wb.z); fma4(acc[7], xv, wb.w);
        }
    }
    float* pslot = partial + (size_t)(z*4 + group*2 + half) * 6144;
#pragma unroll
    for (int ql = 0; ql < 8; ++ql)
        *(float4*)(pslot + ql * 768 + c0) = acc[ql];
}

// small-F: per (q, u-chunk) block; dacc read once; wave-shuffle + LDS reduce; few global atomics
template<int F>
__global__ __launch_bounds__(256) void k_y_small(const float* __restrict__ x,
        const float* __restrict__ ns, const float* __restrict__ dacc,
        float* __restrict__ ys, int s1) {
    const int q = blockIdx.x;
    const int i = q >> 2, j = q & 3;
    const int r1 = 4*s1 + i;
    const int p = 4*(4*DSTT[r1] + j) + KIDX[r1];
    const float* nsp = ns + r1*NN;
    const float* d0 = dacc + (size_t)p*NN;
    const float* d1 = d0 + DSLICE;
    float acc[F];
#pragma unroll
    for (int f = 0; f < F; ++f) acc[f] = 0.f;
    const int u0 = blockIdx.y * 6250;
    for (int u = u0 + threadIdx.x; u < u0 + 6250; u += 256) {
        float w = nsp[u] * (d0[u] + d1[u]);
        const float* xr = x + (size_t)u * F;
#pragma unroll
        for (int f = 0; f < F; ++f) acc[f] += w * xr[f];
    }
#pragma unroll
    for (int f = 0; f < F; ++f)
        for (int off = 32; off > 0; off >>= 1) acc[f] += __shfl_down(acc[f], off, 64);
    __shared__ float red[F];
    if (threadIdx.x < F) red[threadIdx.x] = 0.f;
    __syncthreads();
    if ((threadIdx.x & 63) == 0) {
#pragma unroll
        for (int f = 0; f < F; ++f) atomicAdd(&red[f], acc[f]);
    }
    __syncthreads();
    if (threadIdx.x < F) atomicAdd(&ys[p*768 + threadIdx.x], red[threadIdx.x]);
}

__global__ __launch_bounds__(768) void k_red_y(const float* __restrict__ partial,
                                               const float* __restrict__ ys, float* __restrict__ y) {
    const int p = blockIdx.x;
    const int f = threadIdx.x;
    const int r2 = p >> 2, k = p & 3;
    const int r1 = DSTREL[r2 >> 2][k];
    const int s1 = r1 >> 2;
    float s = ys[p*768 + f];
    if (s1 >= 3) {
        const int group = s1 - 3;
        const int i = r1 & 3;
        const int half = i >> 1;
        const int ql = (i & 1) * 4 + (r2 & 3);
        const float* base = partial + (size_t)(group*2 + half) * 6144 + ql * 768 + f;
        for (int z = 0; z < NZ; ++z) s += base[(size_t)z * 4 * 6144];
    }
    y[p*768 + f] = s;
}

// v[r2][c] = sum_k sum_f y[4*r2+k][f] * W1[r1(k)][f][c]   (no atomics)
__global__ __launch_bounds__(128) void k_v(const float* __restrict__ y,
        const float* __restrict__ W1s, const float* __restrict__ W1f, const float* __restrict__ W1m,
        const float* __restrict__ W1n, const float* __restrict__ W1p, float* __restrict__ v) {
    int r2 = blockIdx.x;
    int c = threadIdx.x;
    float sum = 0.f;
    for (int k = 0; k < 4; ++k) {
        int r1 = DSTREL[r2 >> 2][k];
        int s1 = r1 >> 2;
        int F = FEATS[s1];
        const float* W1 = (s1 == 0 ? W1s : s1 == 1 ? W1f : s1 == 2 ? W1m : s1 == 3 ? W1n : W1p)
                          + (r1 & 3) * F * 128;
        const float* yp = y + (r2*4 + k) * 768;
        for (int f = 0; f < F; ++f) sum += yp[f] * W1[f * 128 + c];
    }
    v[r2 * 128 + c] = sum;
}

// mpart[r2][c] = sum_k (v[r2][k] + S[r2]*bsum1_{src(r2)}[k]) * W2[r2][k][c]
__global__ __launch_bounds__(128) void k_m(const float* __restrict__ v, const float* __restrict__ S,
        const float* __restrict__ b1, const float* __restrict__ W2, float* __restrict__ mpart) {
    int r2 = blockIdx.x;
    int c = threadIdx.x;
    __shared__ float vp[128];
    int s2 = r2 >> 2;
    float b = b1[DSTREL[s2][0]*128 + c] + b1[DSTREL[s2][1]*128 + c]
            + b1[DSTREL[s2][2]*128 + c] + b1[DSTREL[s2][3]*128 + c];
    vp[c] = v[r2*128 + c] + S[r2] * b;
    __syncthreads();
    const float* W2r = W2 + r2 * 16384;
    float sum = 0.f;
    for (int k = 0; k < 128; ++k) sum += vp[k] * W2r[k * 128 + c];
    mpart[r2 * 128 + c] = sum;
}

__global__ __launch_bounds__(128) void k_out(const float* __restrict__ mpart, const float* __restrict__ b2,
        const float* __restrict__ Wfc, const float* __restrict__ bfc, float* __restrict__ out) {
    int c = threadIdx.x;
    __shared__ float ml[128];
    float bs = 0.f, ms = 0.f;
    for (int r2 = 0; r2 < 20; ++r2) { bs += b2[r2 * 128 + c]; ms += mpart[r2 * 128 + c]; }
    float m = (ms + (float)NN * bs) * (1.0f / (5.0f * (float)NN));
    out[c] = m;
    ml[c] = m;
    __syncthreads();
    if (c < 10) {
        float o = bfc[c];
        for (int k = 0; k < 128; ++k) o += ml[k] * Wfc[k * 10 + c];
        out[128 + c] = o;
    }
}

extern "C" void kernel_launch(void* const* d_in, const int* in_sizes, int n_in,
                              void* d_out, int out_size, void* d_ws, size_t ws_size,
                              hipStream_t stream) {
    (void)in_sizes; (void)n_in; (void)out_size;
    const float* xs  = (const float*)d_in[0];
    const float* xf  = (const float*)d_in[1];
    const float* xm  = (const float*)d_in[2];
    const float* xn  = (const float*)d_in[3];
    const float* xp  = (const float*)d_in[4];
    const float* W1s = (const float*)d_in[5];
    const float* W1f = (const float*)d_in[6];
    const float* W1m = (const float*)d_in[7];
    const float* W1n = (const float*)d_in[8];
    const float* W1p = (const float*)d_in[9];
    const float* b1  = (const float*)d_in[10];
    const float* W2  = (const float*)d_in[11];
    const float* b2  = (const float*)d_in[12];
    const float* Wfc = (const float*)d_in[13];
    const float* bfc = (const float*)d_in[14];
    const int* edges = (const int*)d_in[15];
    float* ws = (float*)d_ws;
    int* wsi = (int*)d_ws;
    float* out = (float*)d_out;
    if (ws_size < (size_t)TOTAL_ELEMS * 4) return;

    dim3 t256(256), nb(196, 20);

    // zero YS (6,500,000..6,561,440) and S (6,600,000..6,600,064) in one memset
    hipMemsetAsync(ws + OFF_YS, 0, (size_t)(OFF_S + 64 - OFF_YS) * 4, stream);

    k_hist<<<dim3(ESL_H, NCH_H, 40), dim3(1024), 0, stream>>>(edges, wsi + OFF_HIST);
    k_norms<<<nb, t256, 0, stream>>>(wsi + OFF_HIST, ws + OFF_NS, ws + OFF_ND);
    k_craw<<<dim3(ESL_C, NCH_H, 20), dim3(1024), 0, stream>>>(edges, ws + OFF_ND, ws + OFF_CRAW);
    k_cS<<<nb, t256, 0, stream>>>(ws + OFF_CRAW, ws + OFF_NS, ws + OFF_C, ws + OFF_S);
    k_cc<<<nb, t256, 0, stream>>>(ws + OFF_C, ws + OFF_ND, ws + OFF_CC4);
    k_dacc<<<dim3(ESL_D, NCH_D, 20), dim3(1024), 0, stream>>>(edges, ws + OFF_CC4, ws + OFF_DACC);
    k_y_big<<<dim3(NZ, 2, 2), dim3(192), 0, stream>>>(xn, xp, ws + OFF_NS, ws + OFF_DACC, ws + OFF_PART);
    k_y_small<5><<<dim3(16, 8), t256, 0, stream>>>(xs, ws + OFF_NS, ws + OFF_DACC, ws + OFF_YS, 0);
    k_y_small<16><<<dim3(16, 8), t256, 0, stream>>>(xf, ws + OFF_NS, ws + OFF_DACC, ws + OFF_YS, 1);
    k_y_small<21><<<dim3(16, 8), t256, 0, stream>>>(xm, ws + OFF_NS, ws + OFF_DACC, ws + OFF_YS, 2);
    k_red_y<<<dim3(80), dim3(768), 0, stream>>>(ws + OFF_PART, ws + OFF_YS, ws + OFF_Y);
    k_v<<<dim3(20), dim3(128), 0, stream>>>(ws + OFF_Y, W1s, W1f, W1m, W1n, W1p, ws + OFF_V);
    k_m<<<dim3(20), dim3(128), 0, stream>>>(ws + OFF_V, ws + OFF_S, b1, W2, ws + OFF_MP);
    k_out<<<dim3(1), dim3(128), 0, stream>>>(ws + OFF_MP, b2, Wfc, bfc, out);
}